// Round 7
// baseline (185.557 us; speedup 1.0000x reference)
//
#include <hip/hip_runtime.h>

#define B_TOT 32768
#define OC 30
#define HID 100
#define TAGS 36

// ws layout (dwords):
#define WS_TH  0          // fp16x2[6000]   T tables: ((k*5+g)*100+c)*4+d
#define WS_FC1 6000       // u32[13*2048]   fc1 B packs, ks-major, 2048-dw stride (1792 used/ks)
#define WS_OUT 32624      // u32[3072]      out B packs, ks-major: chunk = ks*3+nt

typedef __attribute__((ext_vector_type(8))) _Float16 half8;
typedef __attribute__((ext_vector_type(2))) _Float16 h2v;
typedef __attribute__((ext_vector_type(4))) float f32x4;

struct __attribute__((packed, aligned(4))) U4A { uint4 v; };   // 4-B-aligned uint4 load

__device__ inline half8 ash8(uint4 u) {
    union { uint4 a; half8 b; } v; v.a = u; return v.b;
}
__device__ inline unsigned int h2u(h2v h) {
    union { h2v a; unsigned int b; } v; v.a = h; return v.b;
}
__device__ inline h2v u2h(unsigned int u) {
    union { unsigned int a; h2v b; } v; v.a = u; return v.b;
}
__device__ inline unsigned int pk_f16(float a, float b) {
    h2v h; h.x = (_Float16)a; h.y = (_Float16)b; return h2u(h);
}
__device__ inline float fast_tanh(float x) {
    float ax = __builtin_fabsf(x);
    float e  = __expf(2.0f * ax);
    float r  = 1.0f - 2.0f * __builtin_amdgcn_rcpf(e + 1.0f);
    return __builtin_copysignf(r, x);
}

// ---------------- prep: fp16 T tables + fp16 MFMA B-frag packs (R2-proven) ----------------
__global__ void prep(const float* __restrict__ conv_w,   // (30,32,3)
                     const float* __restrict__ char_emb, // (100,32)
                     const float* __restrict__ fc1_w,    // (100,400)
                     const float* __restrict__ out_w,    // (36,100)
                     unsigned int* __restrict__ ws) {
    int idx = blockIdx.x * 256 + threadIdx.x;
    if (idx < 6000) {
        // T layout: ((k*5+g)*100+c)*4+d ; dword rd = g*4+d holds oc pair (2rd, 2rd+1)
        int d  = idx & 3;
        int t  = idx >> 2;        // 0..1499
        int c  = t % 100;
        int kg = t / 100;         // 0..14
        int g  = kg % 5, k = kg / 5;
        int rd = g * 4 + d;       // 0..19
        float v[2];
        #pragma unroll
        for (int e = 0; e < 2; ++e) {
            int oc = rd * 2 + e;
            float s = 0.f;
            if (oc < OC) {
                for (int ce = 0; ce < 32; ++ce)
                    s += char_emb[c * 32 + ce] * conv_w[(oc * 32 + ce) * 3 + k];
            }
            v[e] = s;
        }
        ws[WS_TH + idx] = pk_f16(v[0], v[1]);
    } else if (idx < 6000 + 23296) {
        // fc1 B-frag chunks, ks-major: region ks*2048 + (nt*64+lane)*4+dw
        int t = idx - 6000;
        int dw = t & 3, lane = (t >> 2) & 63, chunk = t >> 8;   // chunk 0..90
        int ks = chunk / 7, nt = chunk % 7;
        int j = nt * 16 + (lane & 15);
        int k = ks * 32 + (lane >> 4) * 8 + dw * 2;
        float a = (j < HID && k     < 400) ? fc1_w[j * 400 + k]     : 0.f;
        float b = (j < HID && k + 1 < 400) ? fc1_w[j * 400 + k + 1] : 0.f;
        ws[WS_FC1 + ks * 2048 + (nt * 64 + lane) * 4 + dw] = pk_f16(a, b);
    } else if (idx < 29296 + 3072) {
        // out B-frag chunks, ks-major: chunk = ks*3+nt, linear
        int t = idx - 29296;
        int dw = t & 3, lane = (t >> 2) & 63, chunk = t >> 8;   // chunk 0..11
        int ks = chunk / 3, nt = chunk % 3;
        int j = nt * 16 + (lane & 15);
        int k = ks * 32 + (lane >> 4) * 8 + dw * 2;
        float a = (j < TAGS && k     < HID) ? out_w[j * 100 + k]     : 0.f;
        float b = (j < TAGS && k + 1 < HID) ? out_w[j * 100 + k + 1] : 0.f;
        ws[WS_OUT + t] = pk_f16(a, b);
    }
}

// -------- fused (512 thr, 8 waves, 64 items): emb+conv -> F LDS -> fc1 MFMA (pair-split) -> tanh -> out --------
__global__ __launch_bounds__(512, 4)
void fused(const int*   __restrict__ input,   // (B, 105)
           const float* __restrict__ emb,     // (WV, 50)
           const float* __restrict__ conv_b,  // (30)
           const float* __restrict__ fc1_b,   // (100)
           const float* __restrict__ out_b,   // (36)
           const unsigned int* __restrict__ ws,
           float*       __restrict__ out)     // (B, 36)
{
    __shared__ __align__(16) unsigned int Ths[6000];      // T tables; after conv: B dbuf [2][512 u4] / out-B
    __shared__ __align__(16) unsigned int FL[64 * 212];   // F rows (212-dw stride)

    const int tid  = threadIdx.x;
    const int wv   = tid >> 6;        // 0..7
    const int lane = tid & 63;
    const int ln15 = lane & 15;
    const int quad = lane >> 4;
    const int grp  = wv >> 1;         // 16-item group 0..3
    const int h    = wv & 1;          // pair half
    const int gi0  = blockIdx.x * 64 + grp * 16;   // group base (fc1/out)
    const int ib0  = blockIdx.x * 64 + wv * 8;     // this wave's 8 items (emb/conv)
    unsigned int* Fw8 = &FL[wv * 8 * 212];         // own 8 F rows
    unsigned int* Fg  = &FL[grp * 16 * 212];       // pair's 16 rows (A / H)

    const uint4* srcB = (const uint4*)(ws + WS_FC1);      // uint4 idx: ks*512 + e (e<448 used)

    // ---- stage T tables (block-wide, vectorized) ----
    {
        const uint4* src = (const uint4*)(ws + WS_TH);
        uint4* dst = (uint4*)Ths;
        for (int idx = tid; idx < 1500; idx += 512) dst[idx] = src[idx];
    }
    // prologue fc1-B load for ks=0 (flies through emb/conv)
    uint4 p0{};
    if (tid < 448) p0 = srcB[tid];
    __syncthreads();

    // ---- zero K-pad dwords 200..207 of all 64 rows (one write per thread) ----
    FL[(tid >> 3) * 212 + 200 + (tid & 7)] = 0;

    // ---- word embeddings: own 8 items, two-pass (wid loads, then gathers) ----
    {
        int wid[16];
        #pragma unroll
        for (int j = 0; j < 16; ++j) {
            int idx = lane + j * 64;
            if (idx < 1000) {
                int w = (idx / 25) % 5;
                int i = idx / 125;
                wid[j] = input[(ib0 + i) * 105 + w * 21];
            }
        }
        #pragma unroll
        for (int j = 0; j < 16; ++j) {
            int idx = lane + j * 64;
            if (idx < 1000) {
                int ph = idx % 25;
                int w  = (idx / 25) % 5;
                int i  = idx / 125;
                float2 e = *(const float2*)&emb[wid[j] * 50 + ph * 2];
                Fw8[i * 212 + w * 40 + ph] = pk_f16(e.x, e.y);
            }
        }
    }

    // ---- conv + maxpool: own 8 items = 40 tasks; 4 lanes per (i,w) ----
    {
        const int q4  = lane & 3;
        const int oc0 = q4 * 8;
        h2v bias[4];
        #pragma unroll
        for (int d = 0; d < 4; ++d) {
            int a = oc0 + 2 * d, b = a + 1;
            bias[d].x = (_Float16)(a < OC ? conv_b[a] : 0.f);
            bias[d].y = (_Float16)(b < OC ? conv_b[b] : 0.f);
        }
        const unsigned int* T0 = &Ths[q4 * 400];
        const unsigned int* T1 = &Ths[q4 * 400 + 2000];
        const unsigned int* T2 = &Ths[q4 * 400 + 4000];

        const int tk = lane >> 2;      // task slot 0..15
        uint4 cvA0{}, cvA1{}, cvA2{}, cvA3{}, cvA4{};
        {
            const U4A* q = (const U4A*)&input[(ib0 + tk / 5) * 105 + (tk % 5) * 21 + 1];
            cvA0 = q[0].v; cvA1 = q[1].v; cvA2 = q[2].v; cvA3 = q[3].v; cvA4 = q[4].v;
        }
        #pragma unroll
        for (int it = 0; it < 3; ++it) {
            int task = tk + it * 16;            // 0..47, valid <40
            uint4 cvB0{}, cvB1{}, cvB2{}, cvB3{}, cvB4{};
            if (it < 2) {                       // prefetch next task's chars
                int tn = tk + (it + 1) * 16;
                if (tn < 40) {
                    const U4A* q = (const U4A*)&input[(ib0 + tn / 5) * 105 + (tn % 5) * 21 + 1];
                    cvB0 = q[0].v; cvB1 = q[1].v; cvB2 = q[2].v; cvB3 = q[3].v; cvB4 = q[4].v;
                }
            }
            if (task < 40) {
                int i = task / 5, w = task % 5;
                int c[20];
                c[0]=cvA0.x; c[1]=cvA0.y; c[2]=cvA0.z; c[3]=cvA0.w;
                c[4]=cvA1.x; c[5]=cvA1.y; c[6]=cvA1.z; c[7]=cvA1.w;
                c[8]=cvA2.x; c[9]=cvA2.y; c[10]=cvA2.z; c[11]=cvA2.w;
                c[12]=cvA3.x; c[13]=cvA3.y; c[14]=cvA3.z; c[15]=cvA3.w;
                c[16]=cvA4.x; c[17]=cvA4.y; c[18]=cvA4.z; c[19]=cvA4.w;
                h2v m[4];
                #pragma unroll
                for (int d = 0; d < 4; ++d) { m[d].x = (_Float16)(-30000.f); m[d].y = (_Float16)(-30000.f); }
                #pragma unroll
                for (int p = 0; p < 18; ++p) {
                    uint4 ra = *(const uint4*)&T0[c[p    ] * 4];
                    uint4 rb = *(const uint4*)&T1[c[p + 1] * 4];
                    uint4 rc = *(const uint4*)&T2[c[p + 2] * 4];
                    unsigned int* pa = (unsigned int*)&ra;
                    unsigned int* pb = (unsigned int*)&rb;
                    unsigned int* pc = (unsigned int*)&rc;
                    #pragma unroll
                    for (int d = 0; d < 4; ++d) {
                        h2v s = u2h(pa[d]) + u2h(pb[d]) + u2h(pc[d]);
                        m[d] = __builtin_elementwise_max(m[d], s);
                    }
                }
                int base = i * 212 + w * 40 + 25 + q4 * 4;
                Fw8[base]     = h2u(m[0] + bias[0]);
                Fw8[base + 1] = h2u(m[1] + bias[1]);
                Fw8[base + 2] = h2u(m[2] + bias[2]);
                if (q4 < 3) Fw8[base + 3] = h2u(m[3] + bias[3]);
            }
            cvA0 = cvB0; cvA1 = cvB1; cvA2 = cvB2; cvA3 = cvB3; cvA4 = cvB4;
        }
    }
    __syncthreads();                  // (A) all F rows complete; all conv T reads done

    // ---- preload A-frags (group's 16 rows; both pair waves load identical A) ----
    uint4 af[13];
    {
        const unsigned int* arow = &Fg[ln15 * 212 + quad * 4];
        #pragma unroll
        for (int ks = 0; ks < 13; ++ks) af[ks] = *(const uint4*)(arow + ks * 16);
    }

    // ---- fc1: B double-buffered through dead T region; pair splits 7 n-tiles 4/3 ----
    f32x4 acc[4];
    #pragma unroll
    for (int t = 0; t < 4; ++t) acc[t] = f32x4{0, 0, 0, 0};
    const int nt0 = h * 4;            // first n-tile (0 or 4)

    uint4* Bb = (uint4*)Ths;
    if (tid < 448) Bb[tid] = p0;      // buf0 <- ks0
    __syncthreads();                  // (B) buf0 visible

    #pragma unroll
    for (int ks = 0; ks < 13; ++ks) {
        uint4 n0{};
        if (ks < 12 && tid < 448)     // issue next-chunk load EARLY
            n0 = srcB[(ks + 1) * 512 + tid];
        const uint4* bp = Bb + (ks & 1) * 512;
        half8 a = ash8(af[ks]);
        #pragma unroll
        for (int t = 0; t < 3; ++t)
            acc[t] = __builtin_amdgcn_mfma_f32_16x16x32_f16(a, ash8(bp[(nt0 + t) * 64 + lane]), acc[t], 0, 0, 0);
        if (h == 0)
            acc[3] = __builtin_amdgcn_mfma_f32_16x16x32_f16(a, ash8(bp[3 * 64 + lane]), acc[3], 0, 0, 0);
        if (ks < 12 && tid < 448)     // write LATE (latency hidden by MFMAs)
            Bb[((ks + 1) & 1) * 512 + tid] = n0;
        __syncthreads();
    }

    // ---- out-B staging loads (hidden under tanh epilogue) ----
    const uint4* srcO = (const uint4*)(ws + WS_OUT);
    uint4 og0 = srcO[tid];                                  // chunks 0..7
    uint4 og1{};
    if (tid < 256) og1 = srcO[512 + tid];                   // chunks 8..11

    // ---- epilogue: tanh -> H (group region of FL; pair writes disjoint columns) ----
    unsigned short* Hs = (unsigned short*)Fg;
    {
        // zero H pad cols 100..135 (dwords 50..67 per row): 288 dwords, pair-split
        for (int t2 = lane + h * 64; t2 < 288; t2 += 128) {
            int i = t2 / 18, d = t2 % 18;
            Fg[i * 68 + 50 + d] = 0;
        }
        #pragma unroll
        for (int t = 0; t < 4; ++t) {
            if (h == 1 && t == 3) break;
            int j = (nt0 + t) * 16 + ln15;
            if (j < HID) {
                float bj = fc1_b[j];
                #pragma unroll
                for (int r = 0; r < 4; ++r) {
                    int it = quad * 4 + r;
                    float hv = fast_tanh(acc[t][r] + bj);
                    _Float16 hh = (_Float16)hv;
                    Hs[it * 136 + j] = *reinterpret_cast<unsigned short*>(&hh);
                }
            }
        }
    }

    // ---- commit out-B, one barrier, then out MFMAs (pair splits 3 tiles 2/1) ----
    Bb[tid] = og0;
    if (tid < 256) Bb[512 + tid] = og1;
    __syncthreads();                  // (C) H complete (both waves) + out-B visible

    {
        f32x4 oacc[2];
        oacc[0] = f32x4{0, 0, 0, 0};
        oacc[1] = f32x4{0, 0, 0, 0};
        const int tb0 = h ? 2 : 0;    // tiles {0,1} or {2}
        const int ntt = h ? 1 : 2;
        const int aoff = ln15 * 68 + quad * 4;
        #pragma unroll
        for (int ks = 0; ks < 4; ++ks) {
            half8 a = ash8(*(const uint4*)&Fg[aoff + ks * 16]);
            #pragma unroll
            for (int t = 0; t < 2; ++t)
                if (t < ntt)
                    oacc[t] = __builtin_amdgcn_mfma_f32_16x16x32_f16(a, ash8(Bb[(ks * 3 + tb0 + t) * 64 + lane]), oacc[t], 0, 0, 0);
        }
        #pragma unroll
        for (int t = 0; t < 2; ++t) {
            if (t < ntt) {
                int o = (tb0 + t) * 16 + ln15;
                if (o < TAGS) {
                    float bo = out_b[o];
                    #pragma unroll
                    for (int r = 0; r < 4; ++r) {
                        int it = gi0 + quad * 4 + r;
                        out[it * TAGS + o] = oacc[t][r] + bo;
                    }
                }
            }
        }
    }
}

extern "C" void kernel_launch(void* const* d_in, const int* in_sizes, int n_in,
                              void* d_out, int out_size, void* d_ws, size_t ws_size,
                              hipStream_t stream) {
    const int*   input  = (const int*)  d_in[0];
    const float* emb    = (const float*)d_in[1];
    const float* char_e = (const float*)d_in[2];
    const float* conv_w = (const float*)d_in[3];
    const float* conv_b = (const float*)d_in[4];
    const float* fc1_w  = (const float*)d_in[5];
    const float* fc1_b  = (const float*)d_in[6];
    const float* out_w  = (const float*)d_in[7];
    const float* out_b  = (const float*)d_in[8];
    unsigned int* ws = (unsigned int*)d_ws;

    prep<<<127, 256, 0, stream>>>(conv_w, char_e, fc1_w, out_w, ws);
    fused<<<B_TOT / 64, 512, 0, stream>>>(input, emb, conv_b, fc1_b, out_b, ws, (float*)d_out);
}

// Round 10
// 151.818 us; speedup vs baseline: 1.2222x; 1.2222x over previous
//
#include <hip/hip_runtime.h>

#define B_TOT 32768
#define OC 30
#define HID 100
#define TAGS 36

// ws layout (dwords):
#define WS_TH  0          // fp16x2[6000]   T tables: ((k*5+g)*100+c)*4+d
#define WS_FC1 6000       // u32[13*2048]   fc1 B packs, ks-major, 2048-dw stride (1792 used/ks)
#define WS_OUT 32624      // u32[3072]      out B packs, ks-major: chunk = ks*3+nt

typedef __attribute__((ext_vector_type(8))) _Float16 half8;
typedef __attribute__((ext_vector_type(2))) _Float16 h2v;
typedef __attribute__((ext_vector_type(4))) float f32x4;

struct __attribute__((packed, aligned(4))) U4A { uint4 v; };   // 4-B-aligned uint4 load

__device__ inline half8 ash8(uint4 u) {
    union { uint4 a; half8 b; } v; v.a = u; return v.b;
}
__device__ inline unsigned int h2u(h2v h) {
    union { h2v a; unsigned int b; } v; v.a = h; return v.b;
}
__device__ inline h2v u2h(unsigned int u) {
    union { unsigned int a; h2v b; } v; v.a = u; return v.b;
}
__device__ inline unsigned int pk_f16(float a, float b) {
    h2v h; h.x = (_Float16)a; h.y = (_Float16)b; return h2u(h);
}
__device__ inline float fast_tanh(float x) {
    float ax = __builtin_fabsf(x);
    float e  = __expf(2.0f * ax);
    float r  = 1.0f - 2.0f * __builtin_amdgcn_rcpf(e + 1.0f);
    return __builtin_copysignf(r, x);
}

// ---------------- prep: fp16 T tables + fp16 MFMA B-frag packs (R2-proven) ----------------
__global__ void prep(const float* __restrict__ conv_w,   // (30,32,3)
                     const float* __restrict__ char_emb, // (100,32)
                     const float* __restrict__ fc1_w,    // (100,400)
                     const float* __restrict__ out_w,    // (36,100)
                     unsigned int* __restrict__ ws) {
    int idx = blockIdx.x * 256 + threadIdx.x;
    if (idx < 6000) {
        // T layout: ((k*5+g)*100+c)*4+d ; dword rd = g*4+d holds oc pair (2rd, 2rd+1)
        int d  = idx & 3;
        int t  = idx >> 2;        // 0..1499
        int c  = t % 100;
        int kg = t / 100;         // 0..14
        int g  = kg % 5, k = kg / 5;
        int rd = g * 4 + d;       // 0..19
        float v[2];
        #pragma unroll
        for (int e = 0; e < 2; ++e) {
            int oc = rd * 2 + e;
            float s = 0.f;
            if (oc < OC) {
                for (int ce = 0; ce < 32; ++ce)
                    s += char_emb[c * 32 + ce] * conv_w[(oc * 32 + ce) * 3 + k];
            }
            v[e] = s;
        }
        ws[WS_TH + idx] = pk_f16(v[0], v[1]);
    } else if (idx < 6000 + 23296) {
        // fc1 B-frag chunks, ks-major: region ks*2048 + (nt*64+lane)*4+dw
        int t = idx - 6000;
        int dw = t & 3, lane = (t >> 2) & 63, chunk = t >> 8;   // chunk 0..90
        int ks = chunk / 7, nt = chunk % 7;
        int j = nt * 16 + (lane & 15);
        int k = ks * 32 + (lane >> 4) * 8 + dw * 2;
        float a = (j < HID && k     < 400) ? fc1_w[j * 400 + k]     : 0.f;
        float b = (j < HID && k + 1 < 400) ? fc1_w[j * 400 + k + 1] : 0.f;
        ws[WS_FC1 + ks * 2048 + (nt * 64 + lane) * 4 + dw] = pk_f16(a, b);
    } else if (idx < 29296 + 3072) {
        // out B-frag chunks, ks-major: chunk = ks*3+nt, linear
        int t = idx - 29296;
        int dw = t & 3, lane = (t >> 2) & 63, chunk = t >> 8;   // chunk 0..11
        int ks = chunk / 3, nt = chunk % 3;
        int j = nt * 16 + (lane & 15);
        int k = ks * 32 + (lane >> 4) * 8 + dw * 2;
        float a = (j < TAGS && k     < HID) ? out_w[j * 100 + k]     : 0.f;
        float b = (j < TAGS && k + 1 < HID) ? out_w[j * 100 + k + 1] : 0.f;
        ws[WS_OUT + t] = pk_f16(a, b);
    }
}

// ---- fused (256 thr / 4 waves / 32 items, 51 KB LDS -> 3 blocks/CU): emb+conv -> fc1 (pair-split) -> tanh -> out ----
__global__ __launch_bounds__(256, 3)
void fused(const int*   __restrict__ input,   // (B, 105)
           const float* __restrict__ emb,     // (WV, 50)
           const float* __restrict__ conv_b,  // (30)
           const float* __restrict__ fc1_b,   // (100)
           const float* __restrict__ out_b,   // (36)
           const unsigned int* __restrict__ ws,
           float*       __restrict__ out)     // (B, 36)
{
    __shared__ __align__(16) unsigned int Ths[6000];      // T tables; after conv: B dbuf [2][512 u4] / out-B
    __shared__ __align__(16) unsigned int FL[32 * 212];   // F rows (212-dw stride), 27.1 KB

    const int tid  = threadIdx.x;
    const int wv   = tid >> 6;        // 0..3
    const int lane = tid & 63;
    const int ln15 = lane & 15;
    const int quad = lane >> 4;
    const int grp  = wv >> 1;         // 16-item group 0..1
    const int h    = wv & 1;          // pair half
    const int gi0  = blockIdx.x * 32 + grp * 16;   // group base (fc1/out)
    const int ib0  = blockIdx.x * 32 + wv * 8;     // this wave's 8 items (emb/conv)
    unsigned int* Fw8 = &FL[wv * 8 * 212];         // own 8 F rows
    unsigned int* Fg  = &FL[grp * 16 * 212];       // pair's 16 rows (A / H)

    const uint4* srcB = (const uint4*)(ws + WS_FC1);      // uint4 idx: ks*512 + e
    const int se = wv * 128 + lane;                       // R2-proven bijective staging slot (+64 complement)

    // ---- stage T tables (block-wide, vectorized) ----
    {
        const uint4* src = (const uint4*)(ws + WS_TH);
        uint4* dst = (uint4*)Ths;
        for (int idx = tid; idx < 1500; idx += 256) dst[idx] = src[idx];
    }
    // prologue fc1-B loads for ks=0 (fly through emb/conv)
    uint4 p0 = srcB[se], p1 = srcB[se + 64];
    __syncthreads();

    // ---- zero K-pad dwords 200..207 of all 32 rows (one write per thread) ----
    FL[(tid >> 3) * 212 + 200 + (tid & 7)] = 0;

    // ---- word embeddings: own 8 items, two-pass (wid loads, then gathers) ----
    {
        int wid[16];
        #pragma unroll
        for (int j = 0; j < 16; ++j) {
            int idx = lane + j * 64;
            if (idx < 1000) {
                int w = (idx / 25) % 5;
                int i = idx / 125;
                wid[j] = input[(ib0 + i) * 105 + w * 21];
            }
        }
        #pragma unroll
        for (int j = 0; j < 16; ++j) {
            int idx = lane + j * 64;
            if (idx < 1000) {
                int ph = idx % 25;
                int w  = (idx / 25) % 5;
                int i  = idx / 125;
                float2 e = *(const float2*)&emb[wid[j] * 50 + ph * 2];
                Fw8[i * 212 + w * 40 + ph] = pk_f16(e.x, e.y);
            }
        }
    }

    // ---- conv + maxpool: own 8 items = 40 tasks; 4 lanes per (i,w) ----
    {
        const int q4  = lane & 3;
        const int oc0 = q4 * 8;
        h2v bias[4];
        #pragma unroll
        for (int d = 0; d < 4; ++d) {
            int a = oc0 + 2 * d, b = a + 1;
            bias[d].x = (_Float16)(a < OC ? conv_b[a] : 0.f);
            bias[d].y = (_Float16)(b < OC ? conv_b[b] : 0.f);
        }
        const unsigned int* T0 = &Ths[q4 * 400];
        const unsigned int* T1 = &Ths[q4 * 400 + 2000];
        const unsigned int* T2 = &Ths[q4 * 400 + 4000];

        const int tk = lane >> 2;      // task slot 0..15
        uint4 cvA0{}, cvA1{}, cvA2{}, cvA3{}, cvA4{};
        {
            const U4A* q = (const U4A*)&input[(ib0 + tk / 5) * 105 + (tk % 5) * 21 + 1];
            cvA0 = q[0].v; cvA1 = q[1].v; cvA2 = q[2].v; cvA3 = q[3].v; cvA4 = q[4].v;
        }
        #pragma unroll
        for (int it = 0; it < 3; ++it) {
            int task = tk + it * 16;            // 0..47, valid <40
            uint4 cvB0{}, cvB1{}, cvB2{}, cvB3{}, cvB4{};
            if (it < 2) {                       // prefetch next task's chars
                int tn = tk + (it + 1) * 16;
                if (tn < 40) {
                    const U4A* q = (const U4A*)&input[(ib0 + tn / 5) * 105 + (tn % 5) * 21 + 1];
                    cvB0 = q[0].v; cvB1 = q[1].v; cvB2 = q[2].v; cvB3 = q[3].v; cvB4 = q[4].v;
                }
            }
            if (task < 40) {
                int i = task / 5, w = task % 5;
                int c[20];
                c[0]=cvA0.x; c[1]=cvA0.y; c[2]=cvA0.z; c[3]=cvA0.w;
                c[4]=cvA1.x; c[5]=cvA1.y; c[6]=cvA1.z; c[7]=cvA1.w;
                c[8]=cvA2.x; c[9]=cvA2.y; c[10]=cvA2.z; c[11]=cvA2.w;
                c[12]=cvA3.x; c[13]=cvA3.y; c[14]=cvA3.z; c[15]=cvA3.w;
                c[16]=cvA4.x; c[17]=cvA4.y; c[18]=cvA4.z; c[19]=cvA4.w;
                h2v m[4];
                #pragma unroll
                for (int d = 0; d < 4; ++d) { m[d].x = (_Float16)(-30000.f); m[d].y = (_Float16)(-30000.f); }
                #pragma unroll
                for (int p = 0; p < 18; ++p) {
                    uint4 ra = *(const uint4*)&T0[c[p    ] * 4];
                    uint4 rb = *(const uint4*)&T1[c[p + 1] * 4];
                    uint4 rc = *(const uint4*)&T2[c[p + 2] * 4];
                    unsigned int* pa = (unsigned int*)&ra;
                    unsigned int* pb = (unsigned int*)&rb;
                    unsigned int* pc = (unsigned int*)&rc;
                    #pragma unroll
                    for (int d = 0; d < 4; ++d) {
                        h2v s = u2h(pa[d]) + u2h(pb[d]) + u2h(pc[d]);
                        m[d] = __builtin_elementwise_max(m[d], s);
                    }
                }
                int base = i * 212 + w * 40 + 25 + q4 * 4;
                Fw8[base]     = h2u(m[0] + bias[0]);
                Fw8[base + 1] = h2u(m[1] + bias[1]);
                Fw8[base + 2] = h2u(m[2] + bias[2]);
                if (q4 < 3) Fw8[base + 3] = h2u(m[3] + bias[3]);
            }
            cvA0 = cvB0; cvA1 = cvB1; cvA2 = cvB2; cvA3 = cvB3; cvA4 = cvB4;
        }
    }
    __syncthreads();                  // (A) all F rows complete; all conv T reads done

    // ---- preload A-frags (group's 16 rows; both pair waves load identical A) ----
    uint4 af[13];
    {
        const unsigned int* arow = &Fg[ln15 * 212 + quad * 4];
        #pragma unroll
        for (int ks = 0; ks < 13; ++ks) af[ks] = *(const uint4*)(arow + ks * 16);
    }

    // ---- fc1: B double-buffered through dead T region; pair splits 7 n-tiles 4/3 ----
    f32x4 acc[4];
    #pragma unroll
    for (int t = 0; t < 4; ++t) acc[t] = f32x4{0, 0, 0, 0};
    const int nt0 = h * 4;            // first n-tile (0 or 4)

    uint4* Bb = (uint4*)Ths;
    Bb[se] = p0; Bb[se + 64] = p1;    // buf0 <- ks0
    __syncthreads();                  // (B) buf0 visible

    #pragma unroll
    for (int ks = 0; ks < 13; ++ks) {
        uint4 n0{}, n1{};
        if (ks < 12) {                // issue next-chunk loads EARLY
            n0 = srcB[(ks + 1) * 512 + se];
            n1 = srcB[(ks + 1) * 512 + se + 64];
        }
        const uint4* bp = Bb + (ks & 1) * 512;
        half8 a = ash8(af[ks]);
        #pragma unroll
        for (int t = 0; t < 3; ++t)
            acc[t] = __builtin_amdgcn_mfma_f32_16x16x32_f16(a, ash8(bp[(nt0 + t) * 64 + lane]), acc[t], 0, 0, 0);
        if (h == 0)
            acc[3] = __builtin_amdgcn_mfma_f32_16x16x32_f16(a, ash8(bp[3 * 64 + lane]), acc[3], 0, 0, 0);
        if (ks < 12) {                // write LATE (latency hidden by MFMAs)
            uint4* np = Bb + ((ks + 1) & 1) * 512;
            np[se] = n0; np[se + 64] = n1;
        }
        __syncthreads();
    }

    // ---- out-B staging loads (hidden under tanh epilogue) ----
    const uint4* srcO = (const uint4*)(ws + WS_OUT);
    uint4 o0 = srcO[wv * 192 + lane];
    uint4 o1 = srcO[wv * 192 + 64 + lane];
    uint4 o2 = srcO[wv * 192 + 128 + lane];

    // ---- epilogue: tanh -> H (group region of FL; pair writes disjoint columns) ----
    unsigned short* Hs = (unsigned short*)Fg;
    {
        // zero H pad cols 100..135 (dwords 50..67 per row): 288 dwords, pair-split
        for (int t2 = lane + h * 64; t2 < 288; t2 += 128) {
            int i = t2 / 18, d = t2 % 18;
            Fg[i * 68 + 50 + d] = 0;
        }
        #pragma unroll
        for (int t = 0; t < 4; ++t) {
            if (h == 1 && t == 3) break;
            int j = (nt0 + t) * 16 + ln15;
            if (j < HID) {
                float bj = fc1_b[j];
                #pragma unroll
                for (int r = 0; r < 4; ++r) {
                    int it = quad * 4 + r;
                    float hv = fast_tanh(acc[t][r] + bj);
                    _Float16 hh = (_Float16)hv;
                    Hs[it * 136 + j] = *reinterpret_cast<unsigned short*>(&hh);
                }
            }
        }
    }

    // ---- commit out-B, one barrier, then out MFMAs (pair splits 3 tiles 2/1) ----
    Bb[wv * 192 + lane]       = o0;
    Bb[wv * 192 + 64 + lane]  = o1;
    Bb[wv * 192 + 128 + lane] = o2;
    __syncthreads();                  // (C) H complete (both waves) + out-B visible

    {
        f32x4 oacc[2];
        oacc[0] = f32x4{0, 0, 0, 0};
        oacc[1] = f32x4{0, 0, 0, 0};
        const int tb0 = h ? 2 : 0;    // tiles {0,1} or {2}
        const int ntt = h ? 1 : 2;
        const int aoff = ln15 * 68 + quad * 4;
        #pragma unroll
        for (int ks = 0; ks < 4; ++ks) {
            half8 a = ash8(*(const uint4*)&Fg[aoff + ks * 16]);
            #pragma unroll
            for (int t = 0; t < 2; ++t)
                if (t < ntt)
                    oacc[t] = __builtin_amdgcn_mfma_f32_16x16x32_f16(a, ash8(Bb[(ks * 3 + tb0 + t) * 64 + lane]), oacc[t], 0, 0, 0);
        }
        #pragma unroll
        for (int t = 0; t < 2; ++t) {
            if (t < ntt) {
                int o = (tb0 + t) * 16 + ln15;
                if (o < TAGS) {
                    float bo = out_b[o];
                    #pragma unroll
                    for (int r = 0; r < 4; ++r) {
                        int it = gi0 + quad * 4 + r;
                        out[it * TAGS + o] = oacc[t][r] + bo;
                    }
                }
            }
        }
    }
}

extern "C" void kernel_launch(void* const* d_in, const int* in_sizes, int n_in,
                              void* d_out, int out_size, void* d_ws, size_t ws_size,
                              hipStream_t stream) {
    const int*   input  = (const int*)  d_in[0];
    const float* emb    = (const float*)d_in[1];
    const float* char_e = (const float*)d_in[2];
    const float* conv_w = (const float*)d_in[3];
    const float* conv_b = (const float*)d_in[4];
    const float* fc1_w  = (const float*)d_in[5];
    const float* fc1_b  = (const float*)d_in[6];
    const float* out_w  = (const float*)d_in[7];
    const float* out_b  = (const float*)d_in[8];
    unsigned int* ws = (unsigned int*)d_ws;

    prep<<<127, 256, 0, stream>>>(conv_w, char_e, fc1_w, out_w, ws);
    fused<<<B_TOT / 32, 256, 0, stream>>>(input, emb, conv_b, fc1_b, out_b, ws, (float*)d_out);
}

// Round 11
// 116.293 us; speedup vs baseline: 1.5956x; 1.3055x over previous
//
#include <hip/hip_runtime.h>

#define B_TOT 32768
#define OC 30
#define HID 100
#define TAGS 36

// ws layout (dwords):
#define WS_TH  0          // fp16x2[6000]   T tables: ((k*5+g)*100+c)*4+d
#define WS_FC1 6000       // u32[13*2048]   fc1 B packs, ks-major, 2048-dw stride (1792 used/ks)
#define WS_OUT 32624      // u32[3072]      out B packs, ks-major: chunk = ks*3+nt

typedef __attribute__((ext_vector_type(8))) _Float16 half8;
typedef __attribute__((ext_vector_type(2))) _Float16 h2v;
typedef __attribute__((ext_vector_type(4))) float f32x4;

struct __attribute__((packed, aligned(4))) U4A { uint4 v; };   // 4-B-aligned uint4 load

__device__ inline half8 ash8(uint4 u) {
    union { uint4 a; half8 b; } v; v.a = u; return v.b;
}
__device__ inline unsigned int h2u(h2v h) {
    union { h2v a; unsigned int b; } v; v.a = h; return v.b;
}
__device__ inline h2v u2h(unsigned int u) {
    union { unsigned int a; h2v b; } v; v.a = u; return v.b;
}
__device__ inline unsigned int pk_f16(float a, float b) {
    h2v h; h.x = (_Float16)a; h.y = (_Float16)b; return h2u(h);
}
__device__ inline float fast_tanh(float x) {
    float ax = __builtin_fabsf(x);
    float e  = __expf(2.0f * ax);
    float r  = 1.0f - 2.0f * __builtin_amdgcn_rcpf(e + 1.0f);
    return __builtin_copysignf(r, x);
}

// ---------------- prep: fp16 T tables + fp16 MFMA B-frag packs (R2-proven) ----------------
__global__ void prep(const float* __restrict__ conv_w,   // (30,32,3)
                     const float* __restrict__ char_emb, // (100,32)
                     const float* __restrict__ fc1_w,    // (100,400)
                     const float* __restrict__ out_w,    // (36,100)
                     unsigned int* __restrict__ ws) {
    int idx = blockIdx.x * 256 + threadIdx.x;
    if (idx < 6000) {
        // T layout: ((k*5+g)*100+c)*4+d ; dword rd = g*4+d holds oc pair (2rd, 2rd+1)
        int d  = idx & 3;
        int t  = idx >> 2;        // 0..1499
        int c  = t % 100;
        int kg = t / 100;         // 0..14
        int g  = kg % 5, k = kg / 5;
        int rd = g * 4 + d;       // 0..19
        float v[2];
        #pragma unroll
        for (int e = 0; e < 2; ++e) {
            int oc = rd * 2 + e;
            float s = 0.f;
            if (oc < OC) {
                for (int ce = 0; ce < 32; ++ce)
                    s += char_emb[c * 32 + ce] * conv_w[(oc * 32 + ce) * 3 + k];
            }
            v[e] = s;
        }
        ws[WS_TH + idx] = pk_f16(v[0], v[1]);
    } else if (idx < 6000 + 23296) {
        // fc1 B-frag chunks, ks-major: region ks*2048 + (nt*64+lane)*4+dw
        int t = idx - 6000;
        int dw = t & 3, lane = (t >> 2) & 63, chunk = t >> 8;   // chunk 0..90
        int ks = chunk / 7, nt = chunk % 7;
        int j = nt * 16 + (lane & 15);
        int k = ks * 32 + (lane >> 4) * 8 + dw * 2;
        float a = (j < HID && k     < 400) ? fc1_w[j * 400 + k]     : 0.f;
        float b = (j < HID && k + 1 < 400) ? fc1_w[j * 400 + k + 1] : 0.f;
        ws[WS_FC1 + ks * 2048 + (nt * 64 + lane) * 4 + dw] = pk_f16(a, b);
    } else if (idx < 29296 + 3072) {
        // out B-frag chunks, ks-major: chunk = ks*3+nt, linear
        int t = idx - 29296;
        int dw = t & 3, lane = (t >> 2) & 63, chunk = t >> 8;   // chunk 0..11
        int ks = chunk / 3, nt = chunk % 3;
        int j = nt * 16 + (lane & 15);
        int k = ks * 32 + (lane >> 4) * 8 + dw * 2;
        float a = (j < TAGS && k     < HID) ? out_w[j * 100 + k]     : 0.f;
        float b = (j < TAGS && k + 1 < HID) ? out_w[j * 100 + k + 1] : 0.f;
        ws[WS_OUT + t] = pk_f16(a, b);
    }
}

// ---- fused (256 thr / 4 waves / 32 items, 51 KB LDS): launch_bounds(256,2) -> no reg-split spill;
// ---- occupancy is LDS-capped at 3 blocks/CU = 12 waves/CU with actual ~100-reg usage ----
__global__ __launch_bounds__(256, 2)
void fused(const int*   __restrict__ input,   // (B, 105)
           const float* __restrict__ emb,     // (WV, 50)
           const float* __restrict__ conv_b,  // (30)
           const float* __restrict__ fc1_b,   // (100)
           const float* __restrict__ out_b,   // (36)
           const unsigned int* __restrict__ ws,
           float*       __restrict__ out)     // (B, 36)
{
    __shared__ __align__(16) unsigned int Ths[6000];      // T tables; after conv: B dbuf [2][512 u4] / out-B
    __shared__ __align__(16) unsigned int FL[32 * 212];   // F rows (212-dw stride), 27.1 KB

    const int tid  = threadIdx.x;
    const int wv   = tid >> 6;        // 0..3
    const int lane = tid & 63;
    const int ln15 = lane & 15;
    const int quad = lane >> 4;
    const int grp  = wv >> 1;         // 16-item group 0..1
    const int h    = wv & 1;          // pair half
    const int gi0  = blockIdx.x * 32 + grp * 16;   // group base (fc1/out)
    const int ib0  = blockIdx.x * 32 + wv * 8;     // this wave's 8 items (emb/conv)
    unsigned int* Fw8 = &FL[wv * 8 * 212];         // own 8 F rows
    unsigned int* Fg  = &FL[grp * 16 * 212];       // pair's 16 rows (A / H)

    const uint4* srcB = (const uint4*)(ws + WS_FC1);      // uint4 idx: ks*512 + e
    const int se = wv * 128 + lane;                       // R2-proven bijective staging slot (+64 complement)

    // ---- stage T tables (block-wide, vectorized) ----
    {
        const uint4* src = (const uint4*)(ws + WS_TH);
        uint4* dst = (uint4*)Ths;
        for (int idx = tid; idx < 1500; idx += 256) dst[idx] = src[idx];
    }
    // prologue fc1-B loads for ks=0 (fly through emb/conv)
    uint4 p0 = srcB[se], p1 = srcB[se + 64];
    __syncthreads();

    // ---- zero K-pad dwords 200..207 of all 32 rows (one write per thread) ----
    FL[(tid >> 3) * 212 + 200 + (tid & 7)] = 0;

    // ---- word embeddings: own 8 items, two-pass (wid loads, then gathers) ----
    {
        int wid[16];
        #pragma unroll
        for (int j = 0; j < 16; ++j) {
            int idx = lane + j * 64;
            if (idx < 1000) {
                int w = (idx / 25) % 5;
                int i = idx / 125;
                wid[j] = input[(ib0 + i) * 105 + w * 21];
            }
        }
        #pragma unroll
        for (int j = 0; j < 16; ++j) {
            int idx = lane + j * 64;
            if (idx < 1000) {
                int ph = idx % 25;
                int w  = (idx / 25) % 5;
                int i  = idx / 125;
                float2 e = *(const float2*)&emb[wid[j] * 50 + ph * 2];
                Fw8[i * 212 + w * 40 + ph] = pk_f16(e.x, e.y);
            }
        }
    }

    // ---- conv + maxpool: own 8 items = 40 tasks; 4 lanes per (i,w) ----
    {
        const int q4  = lane & 3;
        const int oc0 = q4 * 8;
        h2v bias[4];
        #pragma unroll
        for (int d = 0; d < 4; ++d) {
            int a = oc0 + 2 * d, b = a + 1;
            bias[d].x = (_Float16)(a < OC ? conv_b[a] : 0.f);
            bias[d].y = (_Float16)(b < OC ? conv_b[b] : 0.f);
        }
        const unsigned int* T0 = &Ths[q4 * 400];
        const unsigned int* T1 = &Ths[q4 * 400 + 2000];
        const unsigned int* T2 = &Ths[q4 * 400 + 4000];

        const int tk = lane >> 2;      // task slot 0..15
        uint4 cvA0{}, cvA1{}, cvA2{}, cvA3{}, cvA4{};
        {
            const U4A* q = (const U4A*)&input[(ib0 + tk / 5) * 105 + (tk % 5) * 21 + 1];
            cvA0 = q[0].v; cvA1 = q[1].v; cvA2 = q[2].v; cvA3 = q[3].v; cvA4 = q[4].v;
        }
        #pragma unroll
        for (int it = 0; it < 3; ++it) {
            int task = tk + it * 16;            // 0..47, valid <40
            uint4 cvB0{}, cvB1{}, cvB2{}, cvB3{}, cvB4{};
            if (it < 2) {                       // prefetch next task's chars
                int tn = tk + (it + 1) * 16;
                if (tn < 40) {
                    const U4A* q = (const U4A*)&input[(ib0 + tn / 5) * 105 + (tn % 5) * 21 + 1];
                    cvB0 = q[0].v; cvB1 = q[1].v; cvB2 = q[2].v; cvB3 = q[3].v; cvB4 = q[4].v;
                }
            }
            if (task < 40) {
                int i = task / 5, w = task % 5;
                int c[20];
                c[0]=cvA0.x; c[1]=cvA0.y; c[2]=cvA0.z; c[3]=cvA0.w;
                c[4]=cvA1.x; c[5]=cvA1.y; c[6]=cvA1.z; c[7]=cvA1.w;
                c[8]=cvA2.x; c[9]=cvA2.y; c[10]=cvA2.z; c[11]=cvA2.w;
                c[12]=cvA3.x; c[13]=cvA3.y; c[14]=cvA3.z; c[15]=cvA3.w;
                c[16]=cvA4.x; c[17]=cvA4.y; c[18]=cvA4.z; c[19]=cvA4.w;
                h2v m[4];
                #pragma unroll
                for (int d = 0; d < 4; ++d) { m[d].x = (_Float16)(-30000.f); m[d].y = (_Float16)(-30000.f); }
                #pragma unroll
                for (int p = 0; p < 18; ++p) {
                    uint4 ra = *(const uint4*)&T0[c[p    ] * 4];
                    uint4 rb = *(const uint4*)&T1[c[p + 1] * 4];
                    uint4 rc = *(const uint4*)&T2[c[p + 2] * 4];
                    unsigned int* pa = (unsigned int*)&ra;
                    unsigned int* pb = (unsigned int*)&rb;
                    unsigned int* pc = (unsigned int*)&rc;
                    #pragma unroll
                    for (int d = 0; d < 4; ++d) {
                        h2v s = u2h(pa[d]) + u2h(pb[d]) + u2h(pc[d]);
                        m[d] = __builtin_elementwise_max(m[d], s);
                    }
                }
                int base = i * 212 + w * 40 + 25 + q4 * 4;
                Fw8[base]     = h2u(m[0] + bias[0]);
                Fw8[base + 1] = h2u(m[1] + bias[1]);
                Fw8[base + 2] = h2u(m[2] + bias[2]);
                if (q4 < 3) Fw8[base + 3] = h2u(m[3] + bias[3]);
            }
            cvA0 = cvB0; cvA1 = cvB1; cvA2 = cvB2; cvA3 = cvB3; cvA4 = cvB4;
        }
    }
    __syncthreads();                  // (A) all F rows complete; all conv T reads done

    // ---- preload A-frags (group's 16 rows; both pair waves load identical A) ----
    uint4 af[13];
    {
        const unsigned int* arow = &Fg[ln15 * 212 + quad * 4];
        #pragma unroll
        for (int ks = 0; ks < 13; ++ks) af[ks] = *(const uint4*)(arow + ks * 16);
    }

    // ---- fc1: B double-buffered through dead T region; pair splits 7 n-tiles 4/3 ----
    f32x4 acc[4];
    #pragma unroll
    for (int t = 0; t < 4; ++t) acc[t] = f32x4{0, 0, 0, 0};
    const int nt0 = h * 4;            // first n-tile (0 or 4)

    uint4* Bb = (uint4*)Ths;
    Bb[se] = p0; Bb[se + 64] = p1;    // buf0 <- ks0
    __syncthreads();                  // (B) buf0 visible

    #pragma unroll
    for (int ks = 0; ks < 13; ++ks) {
        uint4 n0{}, n1{};
        if (ks < 12) {                // issue next-chunk loads EARLY
            n0 = srcB[(ks + 1) * 512 + se];
            n1 = srcB[(ks + 1) * 512 + se + 64];
        }
        const uint4* bp = Bb + (ks & 1) * 512;
        half8 a = ash8(af[ks]);
        #pragma unroll
        for (int t = 0; t < 3; ++t)
            acc[t] = __builtin_amdgcn_mfma_f32_16x16x32_f16(a, ash8(bp[(nt0 + t) * 64 + lane]), acc[t], 0, 0, 0);
        if (h == 0)
            acc[3] = __builtin_amdgcn_mfma_f32_16x16x32_f16(a, ash8(bp[3 * 64 + lane]), acc[3], 0, 0, 0);
        if (ks < 12) {                // write LATE (latency hidden by MFMAs)
            uint4* np = Bb + ((ks + 1) & 1) * 512;
            np[se] = n0; np[se + 64] = n1;
        }
        __syncthreads();
    }

    // ---- out-B staging loads (hidden under tanh epilogue) ----
    const uint4* srcO = (const uint4*)(ws + WS_OUT);
    uint4 o0 = srcO[wv * 192 + lane];
    uint4 o1 = srcO[wv * 192 + 64 + lane];
    uint4 o2 = srcO[wv * 192 + 128 + lane];

    // ---- epilogue: tanh -> H (group region of FL; pair writes disjoint columns) ----
    unsigned short* Hs = (unsigned short*)Fg;
    {
        // zero H pad cols 100..135 (dwords 50..67 per row): 288 dwords, pair-split
        for (int t2 = lane + h * 64; t2 < 288; t2 += 128) {
            int i = t2 / 18, d = t2 % 18;
            Fg[i * 68 + 50 + d] = 0;
        }
        #pragma unroll
        for (int t = 0; t < 4; ++t) {
            if (h == 1 && t == 3) break;
            int j = (nt0 + t) * 16 + ln15;
            if (j < HID) {
                float bj = fc1_b[j];
                #pragma unroll
                for (int r = 0; r < 4; ++r) {
                    int it = quad * 4 + r;
                    float hv = fast_tanh(acc[t][r] + bj);
                    _Float16 hh = (_Float16)hv;
                    Hs[it * 136 + j] = *reinterpret_cast<unsigned short*>(&hh);
                }
            }
        }
    }

    // ---- commit out-B, one barrier, then out MFMAs (pair splits 3 tiles 2/1) ----
    Bb[wv * 192 + lane]       = o0;
    Bb[wv * 192 + 64 + lane]  = o1;
    Bb[wv * 192 + 128 + lane] = o2;
    __syncthreads();                  // (C) H complete (both waves) + out-B visible

    {
        f32x4 oacc[2];
        oacc[0] = f32x4{0, 0, 0, 0};
        oacc[1] = f32x4{0, 0, 0, 0};
        const int tb0 = h ? 2 : 0;    // tiles {0,1} or {2}
        const int ntt = h ? 1 : 2;
        const int aoff = ln15 * 68 + quad * 4;
        #pragma unroll
        for (int ks = 0; ks < 4; ++ks) {
            half8 a = ash8(*(const uint4*)&Fg[aoff + ks * 16]);
            #pragma unroll
            for (int t = 0; t < 2; ++t)
                if (t < ntt)
                    oacc[t] = __builtin_amdgcn_mfma_f32_16x16x32_f16(a, ash8(Bb[(ks * 3 + tb0 + t) * 64 + lane]), oacc[t], 0, 0, 0);
        }
        #pragma unroll
        for (int t = 0; t < 2; ++t) {
            if (t < ntt) {
                int o = (tb0 + t) * 16 + ln15;
                if (o < TAGS) {
                    float bo = out_b[o];
                    #pragma unroll
                    for (int r = 0; r < 4; ++r) {
                        int it = gi0 + quad * 4 + r;
                        out[it * TAGS + o] = oacc[t][r] + bo;
                    }
                }
            }
        }
    }
}

extern "C" void kernel_launch(void* const* d_in, const int* in_sizes, int n_in,
                              void* d_out, int out_size, void* d_ws, size_t ws_size,
                              hipStream_t stream) {
    const int*   input  = (const int*)  d_in[0];
    const float* emb    = (const float*)d_in[1];
    const float* char_e = (const float*)d_in[2];
    const float* conv_w = (const float*)d_in[3];
    const float* conv_b = (const float*)d_in[4];
    const float* fc1_w  = (const float*)d_in[5];
    const float* fc1_b  = (const float*)d_in[6];
    const float* out_w  = (const float*)d_in[7];
    const float* out_b  = (const float*)d_in[8];
    unsigned int* ws = (unsigned int*)d_ws;

    prep<<<127, 256, 0, stream>>>(conv_w, char_e, fc1_w, out_w, ws);
    fused<<<B_TOT / 32, 256, 0, stream>>>(input, emb, conv_b, fc1_b, out_b, ws, (float*)d_out);
}

// Round 12
// 110.786 us; speedup vs baseline: 1.6749x; 1.0497x over previous
//
#include <hip/hip_runtime.h>

#define B_TOT 32768
#define OC 30
#define HID 100
#define TAGS 36

// ws layout (dwords):
#define WS_TH  0          // fp16x2[6000]   T tables: ((k*5+g)*100+c)*4+d
#define WS_FC1 6000       // u32[13*2048]   fc1 B packs, ks-major, 2048-dw stride (1792 used/ks)
#define WS_OUT 32624      // u32[3072]      out B packs, ks-major: chunk = ks*3+nt

typedef __attribute__((ext_vector_type(8))) _Float16 half8;
typedef __attribute__((ext_vector_type(2))) _Float16 h2v;
typedef __attribute__((ext_vector_type(4))) float f32x4;

struct __attribute__((packed, aligned(4))) U4A { uint4 v; };   // 4-B-aligned uint4 load

__device__ inline half8 ash8(uint4 u) {
    union { uint4 a; half8 b; } v; v.a = u; return v.b;
}
__device__ inline unsigned int h2u(h2v h) {
    union { h2v a; unsigned int b; } v; v.a = h; return v.b;
}
__device__ inline h2v u2h(unsigned int u) {
    union { unsigned int a; h2v b; } v; v.a = u; return v.b;
}
__device__ inline unsigned int pk_f16(float a, float b) {
    h2v h; h.x = (_Float16)a; h.y = (_Float16)b; return h2u(h);
}
__device__ inline float fast_tanh(float x) {
    float ax = __builtin_fabsf(x);
    float e  = __expf(2.0f * ax);
    float r  = 1.0f - 2.0f * __builtin_amdgcn_rcpf(e + 1.0f);
    return __builtin_copysignf(r, x);
}

// ---------------- prep: fp16 T tables + fp16 MFMA B-frag packs (R2-proven) ----------------
__global__ void prep(const float* __restrict__ conv_w,   // (30,32,3)
                     const float* __restrict__ char_emb, // (100,32)
                     const float* __restrict__ fc1_w,    // (100,400)
                     const float* __restrict__ out_w,    // (36,100)
                     unsigned int* __restrict__ ws) {
    int idx = blockIdx.x * 256 + threadIdx.x;
    if (idx < 6000) {
        // T layout: ((k*5+g)*100+c)*4+d ; dword rd = g*4+d holds oc pair (2rd, 2rd+1)
        int d  = idx & 3;
        int t  = idx >> 2;        // 0..1499
        int c  = t % 100;
        int kg = t / 100;         // 0..14
        int g  = kg % 5, k = kg / 5;
        int rd = g * 4 + d;       // 0..19
        float v[2];
        #pragma unroll
        for (int e = 0; e < 2; ++e) {
            int oc = rd * 2 + e;
            float s = 0.f;
            if (oc < OC) {
                for (int ce = 0; ce < 32; ++ce)
                    s += char_emb[c * 32 + ce] * conv_w[(oc * 32 + ce) * 3 + k];
            }
            v[e] = s;
        }
        ws[WS_TH + idx] = pk_f16(v[0], v[1]);
    } else if (idx < 6000 + 23296) {
        // fc1 B-frag chunks, ks-major: region ks*2048 + (nt*64+lane)*4+dw
        int t = idx - 6000;
        int dw = t & 3, lane = (t >> 2) & 63, chunk = t >> 8;   // chunk 0..90
        int ks = chunk / 7, nt = chunk % 7;
        int j = nt * 16 + (lane & 15);
        int k = ks * 32 + (lane >> 4) * 8 + dw * 2;
        float a = (j < HID && k     < 400) ? fc1_w[j * 400 + k]     : 0.f;
        float b = (j < HID && k + 1 < 400) ? fc1_w[j * 400 + k + 1] : 0.f;
        ws[WS_FC1 + ks * 2048 + (nt * 64 + lane) * 4 + dw] = pk_f16(a, b);
    } else if (idx < 29296 + 3072) {
        // out B-frag chunks, ks-major: chunk = ks*3+nt, linear
        int t = idx - 29296;
        int dw = t & 3, lane = (t >> 2) & 63, chunk = t >> 8;   // chunk 0..11
        int ks = chunk / 3, nt = chunk % 3;
        int j = nt * 16 + (lane & 15);
        int k = ks * 32 + (lane >> 4) * 8 + dw * 2;
        float a = (j < TAGS && k     < HID) ? out_w[j * 100 + k]     : 0.f;
        float b = (j < TAGS && k + 1 < HID) ? out_w[j * 100 + k + 1] : 0.f;
        ws[WS_OUT + t] = pk_f16(a, b);
    }
}

// ---------------- fused (R6 base): emb+conv -> F in LDS -> fc1 MFMA (3-ring B) -> tanh -> out ----------------
__global__ __launch_bounds__(256, 2)
void fused(const int*   __restrict__ input,   // (B, 105)
           const float* __restrict__ emb,     // (WV, 50)
           const float* __restrict__ conv_b,  // (30)
           const float* __restrict__ fc1_b,   // (100)
           const float* __restrict__ out_b,   // (36)
           const unsigned int* __restrict__ ws,
           float*       __restrict__ out)     // (B, 36)
{
    __shared__ __align__(16) unsigned int Ths[6000];      // T tables; after conv: B ring [3][448 u4] / out-B
    __shared__ __align__(16) unsigned int FL[64 * 212];   // F rows (212-dw stride)

    const int tid  = threadIdx.x;
    const int wv   = tid >> 6;
    const int lane = tid & 63;
    const int ln15 = lane & 15;
    const int quad = lane >> 4;
    const int gi0  = blockIdx.x * 64 + wv * 16;
    const bool lo192 = (tid < 192);
    unsigned int* Fw = &FL[wv * (16 * 212)];

    const uint4* srcB = (const uint4*)(ws + WS_FC1);      // uint4 idx: ks*512 + e, e in [0,448)

    // ---- stage T tables (block-wide, vectorized) ----
    {
        const uint4* src = (const uint4*)(ws + WS_TH);
        uint4* dst = (uint4*)Ths;
        for (int idx = tid; idx < 1500; idx += 256) dst[idx] = src[idx];
    }
    // prologue B loads for ks=0 (pure global loads, fly during emb/conv); 448-u4 bijective map
    uint4 z4 = {0, 0, 0, 0};
    uint4 p0 = srcB[tid], p1 = lo192 ? srcB[256 + tid] : z4;
    __syncthreads();

    // ---- zero K-pad dwords 200..207 of this wave's 16 rows ----
    #pragma unroll
    for (int r = 0; r < 2; ++r) {
        int idx = lane + r * 64;
        Fw[(idx >> 3) * 212 + 200 + (idx & 7)] = 0;
    }

    // ---- word embeddings: two-pass (all wid loads issued, then all gathers) ----
    {
        int wid[32];
        #pragma unroll
        for (int j = 0; j < 32; ++j) {
            int idx = lane + j * 64;
            if (idx < 2000) {
                int w = (idx / 25) % 5;
                int i = idx / 125;
                wid[j] = input[(gi0 + i) * 105 + w * 21];
            }
        }
        #pragma unroll
        for (int j = 0; j < 32; ++j) {
            int idx = lane + j * 64;
            if (idx < 2000) {
                int ph = idx % 25;
                int w  = (idx / 25) % 5;
                int i  = idx / 125;
                float2 e = *(const float2*)&emb[wid[j] * 50 + ph * 2];
                Fw[i * 212 + w * 40 + ph] = pk_f16(e.x, e.y);
            }
        }
    }

    // ---- conv + maxpool: 4 lanes per (i,w), lane = 8 oc; 5 tasks per lane ----
    {
        const int q4  = lane & 3;
        const int oc0 = q4 * 8;
        h2v bias[4];
        #pragma unroll
        for (int d = 0; d < 4; ++d) {
            int a = oc0 + 2 * d, b = a + 1;
            bias[d].x = (_Float16)(a < OC ? conv_b[a] : 0.f);
            bias[d].y = (_Float16)(b < OC ? conv_b[b] : 0.f);
        }
        const unsigned int* T0 = &Ths[q4 * 400];
        const unsigned int* T1 = &Ths[q4 * 400 + 2000];
        const unsigned int* T2 = &Ths[q4 * 400 + 4000];

        const int tk = lane >> 2;
        uint4 cvA0, cvA1, cvA2, cvA3, cvA4;
        {
            const U4A* q = (const U4A*)&input[(gi0 + tk / 5) * 105 + (tk % 5) * 21 + 1];
            cvA0 = q[0].v; cvA1 = q[1].v; cvA2 = q[2].v; cvA3 = q[3].v; cvA4 = q[4].v;
        }
        #pragma unroll
        for (int it = 0; it < 5; ++it) {
            int task = tk + it * 16;            // 0..79
            int i = task / 5, w = task % 5;
            uint4 cvB0, cvB1, cvB2, cvB3, cvB4;
            if (it < 4) {                       // issue next task's chars EARLY
                int tn = tk + (it + 1) * 16;
                const U4A* q = (const U4A*)&input[(gi0 + tn / 5) * 105 + (tn % 5) * 21 + 1];
                cvB0 = q[0].v; cvB1 = q[1].v; cvB2 = q[2].v; cvB3 = q[3].v; cvB4 = q[4].v;
            }
            int c[20];
            c[0]=cvA0.x; c[1]=cvA0.y; c[2]=cvA0.z; c[3]=cvA0.w;
            c[4]=cvA1.x; c[5]=cvA1.y; c[6]=cvA1.z; c[7]=cvA1.w;
            c[8]=cvA2.x; c[9]=cvA2.y; c[10]=cvA2.z; c[11]=cvA2.w;
            c[12]=cvA3.x; c[13]=cvA3.y; c[14]=cvA3.z; c[15]=cvA3.w;
            c[16]=cvA4.x; c[17]=cvA4.y; c[18]=cvA4.z; c[19]=cvA4.w;
            h2v m[4];
            #pragma unroll
            for (int d = 0; d < 4; ++d) { m[d].x = (_Float16)(-30000.f); m[d].y = (_Float16)(-30000.f); }
            #pragma unroll
            for (int p = 0; p < 18; ++p) {
                uint4 ra = *(const uint4*)&T0[c[p    ] * 4];
                uint4 rb = *(const uint4*)&T1[c[p + 1] * 4];
                uint4 rc = *(const uint4*)&T2[c[p + 2] * 4];
                unsigned int* pa = (unsigned int*)&ra;
                unsigned int* pb = (unsigned int*)&rb;
                unsigned int* pc = (unsigned int*)&rc;
                #pragma unroll
                for (int d = 0; d < 4; ++d) {
                    h2v s = u2h(pa[d]) + u2h(pb[d]) + u2h(pc[d]);
                    m[d] = __builtin_elementwise_max(m[d], s);
                }
            }
            int base = i * 212 + w * 40 + 25 + q4 * 4;
            Fw[base]     = h2u(m[0] + bias[0]);
            Fw[base + 1] = h2u(m[1] + bias[1]);
            Fw[base + 2] = h2u(m[2] + bias[2]);
            if (q4 < 3) Fw[base + 3] = h2u(m[3] + bias[3]);
            cvA0 = cvB0; cvA1 = cvB1; cvA2 = cvB2; cvA3 = cvB3; cvA4 = cvB4;
        }
    }

    // ---- preload A-frags (own-wave LDS writes are visible in-order) ----
    uint4 af[13];
    {
        const unsigned int* arow = &Fw[ln15 * 212 + quad * 4];
        #pragma unroll
        for (int ks = 0; ks < 13; ++ks) af[ks] = *(const uint4*)(arow + ks * 16);
    }

    // ---- fc1: 3-buffer ring (448-u4 stride) in dead T region, prefetch distance 2 ----
    f32x4 acc[7];
    #pragma unroll
    for (int t = 0; t < 7; ++t) acc[t] = f32x4{0, 0, 0, 0};

    uint4* Bb = (uint4*)Ths;
    __syncthreads();                       // (A) all conv reads of Ths done
    Bb[tid] = p0; if (lo192) Bb[256 + tid] = p1;            // buf0 <- ks0
    uint4 f0 = srcB[512 + tid];                             // ks1 in flight (issued post-conv)
    uint4 f1 = lo192 ? srcB[512 + 256 + tid] : z4;
    __syncthreads();                       // (B) buf0 visible

    #pragma unroll
    for (int ks = 0; ks < 13; ++ks) {
        uint4 n0 = z4, n1 = z4;
        if (ks < 11) {                     // issue ks+2 loads EARLY
            n0 = srcB[(ks + 2) * 512 + tid];
            if (lo192) n1 = srcB[(ks + 2) * 512 + 256 + tid];
        }
        const uint4* bp = Bb + (ks % 3) * 448;
        half8 a = ash8(af[ks]);
        #pragma unroll
        for (int t = 0; t < 7; ++t)
            acc[t] = __builtin_amdgcn_mfma_f32_16x16x32_f16(a, ash8(bp[t * 64 + lane]), acc[t], 0, 0, 0);
        if (ks < 12) {                     // write ks+1 (loaded one full iteration ago)
            uint4* np = Bb + ((ks + 1) % 3) * 448;
            np[tid] = f0;
            if (lo192) np[256 + tid] = f1;
        }
        f0 = n0; f1 = n1;
        __syncthreads();
    }

    // ---- out-B staging loads (hidden under tanh epilogue) ----
    const uint4* srcO = (const uint4*)(ws + WS_OUT);
    uint4 o0 = srcO[wv * 192 + lane];
    uint4 o1 = srcO[wv * 192 + 64 + lane];
    uint4 o2 = srcO[wv * 192 + 128 + lane];

    // ---- epilogue: tanh -> Hh (aliased onto own F region; in-order DS, no barrier) ----
    unsigned int* Hw = Fw;
    {
        for (int t2 = lane; t2 < 224; t2 += 64) {
            int i = t2 / 14, d = t2 % 14;
            Hw[i * 68 + 50 + d] = 0;
        }
        unsigned short* Hs = (unsigned short*)Hw;
        #pragma unroll
        for (int t = 0; t < 7; ++t) {
            int j = t * 16 + ln15;
            if (j < HID) {
                float bj = fc1_b[j];
                #pragma unroll
                for (int r = 0; r < 4; ++r) {
                    int it = quad * 4 + r;
                    float hv = fast_tanh(acc[t][r] + bj);
                    _Float16 h = (_Float16)hv;
                    Hs[it * 136 + j] = *reinterpret_cast<unsigned short*>(&h);
                }
            }
        }
    }

    // ---- commit out-B to LDS, one barrier, then out MFMAs ----
    Bb[wv * 192 + lane]       = o0;
    Bb[wv * 192 + 64 + lane]  = o1;
    Bb[wv * 192 + 128 + lane] = o2;
    __syncthreads();

    {
        f32x4 oacc[3];
        #pragma unroll
        for (int t = 0; t < 3; ++t) oacc[t] = f32x4{0, 0, 0, 0};
        const int aoff = ln15 * 68 + quad * 4;
        #pragma unroll
        for (int ks = 0; ks < 4; ++ks) {
            half8 a = ash8(*(const uint4*)&Hw[aoff + ks * 16]);
            #pragma unroll
            for (int t = 0; t < 3; ++t) {
                uint4 bv = Bb[(ks * 3 + t) * 64 + lane];
                oacc[t] = __builtin_amdgcn_mfma_f32_16x16x32_f16(a, ash8(bv), oacc[t], 0, 0, 0);
            }
        }
        #pragma unroll
        for (int t = 0; t < 3; ++t) {
            int o = t * 16 + ln15;
            if (o < TAGS) {
                float bo = out_b[o];
                #pragma unroll
                for (int r = 0; r < 4; ++r) {
                    int it = gi0 + quad * 4 + r;
                    out[it * TAGS + o] = oacc[t][r] + bo;
                }
            }
        }
    }
}

extern "C" void kernel_launch(void* const* d_in, const int* in_sizes, int n_in,
                              void* d_out, int out_size, void* d_ws, size_t ws_size,
                              hipStream_t stream) {
    const int*   input  = (const int*)  d_in[0];
    const float* emb    = (const float*)d_in[1];
    const float* char_e = (const float*)d_in[2];
    const float* conv_w = (const float*)d_in[3];
    const float* conv_b = (const float*)d_in[4];
    const float* fc1_w  = (const float*)d_in[5];
    const float* fc1_b  = (const float*)d_in[6];
    const float* out_w  = (const float*)d_in[7];
    const float* out_b  = (const float*)d_in[8];
    unsigned int* ws = (unsigned int*)d_ws;

    prep<<<127, 256, 0, stream>>>(conv_w, char_e, fc1_w, out_w, ws);
    fused<<<B_TOT / 64, 256, 0, stream>>>(input, emb, conv_b, fc1_b, out_b, ws, (float*)d_out);
}